// Round 5
// baseline (249.818 us; speedup 1.0000x reference)
//
#include <hip/hip_runtime.h>
#include <hip/hip_bf16.h>
#include <math.h>

// SpatialSelfAttention — B=16, C=512, HW=1024, fp32 in/out, bf16 MFMA internals.
//
// Softmax trick: scaled scores ~ N(0,1), exp() without max-subtraction safe ->
// softmax fuses into GEMM epilogues. Round-9: l (row sums) no longer computed
// in the S epilogue; the O GEMM computes them itself via a ones-MFMA.
//
// Round-9 changes (theory: LDS read datapath is the serial resource —
// measured 370 cy/block-step ≈ 385 cy of ds_read_b128 at 85 B/cy; all three
// K-loop structures plateaued at the same 42-46 µs/GEMM):
//   * Block tile 128x256, wave tile 128x64 (4 waves, column split):
//     12 KB LDS reads per wave-step for 2x FLOPs -> 25% less LDS traffic
//     per FLOP ((128+64)/(128*64) vs (64+64)/(64*64)). LDS 72 KB triple-
//     buffered, 2 blocks/CU, counted vmcnt(6) depth-2 pipeline (round-8).
//   * Ones-MFMA row-sum: S epilogue's 160 shfl_xor/thread (cross-lane ops
//     use the LDS datapath) + atomics + lsum buffer deleted. O GEMM
//     accumulates acc1[mt] = mfma(af, ones, acc1) -> l[row] lands in C-layout
//     lane positions, zero cross-lane, on the ~20%-busy MFMA pipe.
//   * Kept: 2-bit slot swizzle f(row)=(row>>1)&3 (bank-verified), qkv fusion,
//     XCD decode, gload_lds16 staging.

typedef __bf16 bf16x8 __attribute__((ext_vector_type(8)));
typedef float  f32x16 __attribute__((ext_vector_type(16)));

__device__ __forceinline__ unsigned short f2bf(float f) {
    unsigned u = __float_as_uint(f);
    u += 0x7fff + ((u >> 16) & 1);          // round-to-nearest-even
    return (unsigned short)(u >> 16);
}

__device__ __forceinline__ void gload_lds16(const void* g, void* l) {
    __builtin_amdgcn_global_load_lds(
        (const __attribute__((address_space(1))) void*)g,
        (__attribute__((address_space(3))) void*)l, 16, 0, 0);
}

struct GemmP {
    const unsigned short* A;
    const unsigned short* B;
    void* C;
    const float* bias;
    const float* resid;
    int M, N, K, ldA, ldB;
    long sA, sB, sC, sR;
    int ln_nn, ln_pb;
    float scale;
};

// ---------------------------------------------------------------------------
// MFMA GEMM body: C[m,n] = sum_k A[m,k]*B[n,k], 16 batches, 1-D grid.
// Block tile 128 (M) x 256 (N); wave w owns cols w*64..w*64+63, all 128 rows.
// Decode: xcd = L&7 owns batches {2*xcd, 2*xcd+1}; within-batch tiles
// row-major, M-tile stride 128, N-tile stride 256.
// BIAS_MODE: 0 none, 1 per-m, 2 per-n.
// EXPM: 0 none; 1 = out bf16 exp(val*scale); 2 = out scaled by 1/rowsum
//       where rowsum is accumulated in-kernel via ones-MFMA.
// ---------------------------------------------------------------------------
template<bool OUT_F32, int BIAS_MODE, bool RESID, int EXPM>
__device__ __forceinline__ void gemm_body(const GemmP p, int L,
                                          unsigned short* Als,
                                          unsigned short* Bls)
{
    // ---- XCD-aware decode ----
    const int xcd = L & 7;
    const int idx = L >> 3;
    const int bz  = xcd * 2 + (idx >> p.ln_pb);
    const int w   = idx & ((1 << p.ln_pb) - 1);
    const int m0  = (w >> p.ln_nn) << 7;                  // M-tile * 128
    const int n0  = (w & ((1 << p.ln_nn) - 1)) << 8;      // N-tile * 256

    const unsigned short* A = p.A + bz * p.sA;
    const unsigned short* B = p.B + bz * p.sB;

    const int tid  = threadIdx.x;
    const int lane = tid & 63;
    const int wave = tid >> 6;       // 0..3 (column group)

    // staging coords: chunk = 16 rows x 32 k = 1024 B; lane -> (row, slot)
    // slot pre-swizzled in GLOBAL k so LDS phys slot s holds logical
    // s ^ f(row), f(row) = (row>>1)&3 (gload_lds LDS dest is DMA-linear).
    const int ar = lane >> 2;                              // 0..15
    const int ak = (((lane & 3) ^ ((ar >> 1) & 3))) * 8;   // swizzled k offset

    // A panel [128][32]: wave stages chunks {w, w+4}; B panel [256][32]:
    // chunks {w, w+4, w+8, w+12}. Chunk c covers rows c*16..c*16+15.
    const unsigned short* agp = A + (long)(m0 + wave * 16 + ar) * p.ldA + ak;
    const unsigned short* bgp = B + (long)(n0 + wave * 16 + ar) * p.ldB + ak;
    const long aj = 64L * p.ldA;       // +64 rows
    const long bj = 64L * p.ldB;

    // 32x32x16 fragment coords: m/n = lane&31, k = (lane>>5)*8 + j
    const int ln31 = lane & 31;
    const int hi   = lane >> 5;
    const int swz  = ((ln31 >> 1) & 3) << 3;  // ushort-offset XOR (2-bit slot)
    const int koff0 = (hi * 8) ^ swz;         // ks=0 slot
    const int koff1 = (16 + hi * 8) ^ swz;    // ks=1 slot

    f32x16 acc[4][2] = {};
    f32x16 acc1[4] = {};                      // row-sums (EXPM==2 only)
    bf16x8 ones;
    if constexpr (EXPM == 2) {
        #pragma unroll
        for (int i = 0; i < 8; ++i) ones[i] = (__bf16)1.0f;
    }

    const int nsteps = p.K >> 5;              // BK=32; 16 or 32 steps

    // stage A panel (8 KB) + B panel (16 KB): 6 gload_lds per wave
    auto STAGE = [&](int sel) {
        unsigned short* a0 = Als + sel * 4096;
        unsigned short* b0 = Bls + sel * 8192;
        gload_lds16(agp,          a0 + wave * 512);
        gload_lds16(agp + aj,     a0 + (wave + 4) * 512);
        gload_lds16(bgp,          b0 + wave * 512);
        gload_lds16(bgp + bj,     b0 + (wave + 4) * 512);
        gload_lds16(bgp + 2 * bj, b0 + (wave + 8) * 512);
        gload_lds16(bgp + 3 * bj, b0 + (wave + 12) * 512);
        agp += 32; bgp += 32;
    };

    // ds_read fragments from buffer sel, run 16 (+4 ones) MFMAs
    auto COMPUTE = [&](int sel) {
        const unsigned short* Ap = Als + sel * 4096;
        const unsigned short* Bp = Bls + sel * 8192;
        #pragma unroll
        for (int ks = 0; ks < 2; ++ks) {
            const int ko = ks ? koff1 : koff0;
            bf16x8 af[4], bfr[2];
            #pragma unroll
            for (int mt = 0; mt < 4; ++mt)
                af[mt] = *(const bf16x8*)&Ap[(mt * 32 + ln31) * 32 + ko];
            #pragma unroll
            for (int nt = 0; nt < 2; ++nt)
                bfr[nt] = *(const bf16x8*)&Bp[(wave * 64 + nt * 32 + ln31) * 32 + ko];
            if constexpr (EXPM == 2) {
                #pragma unroll
                for (int mt = 0; mt < 4; ++mt)
                    acc1[mt] = __builtin_amdgcn_mfma_f32_32x32x16_bf16(
                        af[mt], ones, acc1[mt], 0, 0, 0);
            }
            #pragma unroll
            for (int mt = 0; mt < 4; ++mt)
                #pragma unroll
                for (int nt = 0; nt < 2; ++nt)
                    acc[mt][nt] = __builtin_amdgcn_mfma_f32_32x32x16_bf16(
                        af[mt], bfr[nt], acc[mt][nt], 0, 0, 0);
        }
    };

    // prologue: prefetch steps 0 and 1 (12 loads outstanding per wave)
    STAGE(0);
    STAGE(1);

    // counted-vmcnt main loop (round-8 structure, 6 loads/step):
    //   entry outstanding: {t:6 (oldest), t+1:6}; vmcnt(6) retires buf[t];
    //   barrier -> all waves' buf[t] landed; STAGE(t+2) overwrites the
    //   buffer whose readers all passed the previous barrier.
    int bc = 0, bn = 1, bs = 2;
    for (int t = 0; t < nsteps - 1; ++t) {
        __builtin_amdgcn_sched_barrier(0);
        asm volatile("s_waitcnt vmcnt(6)" ::: "memory");
        __builtin_amdgcn_s_barrier();
        asm volatile("" ::: "memory");
        __builtin_amdgcn_sched_barrier(0);
        if (t + 2 < nsteps) STAGE(bs);
        COMPUTE(bc);
        const int tmp = bc; bc = bn; bn = bs; bs = tmp;
    }
    // peeled last step: only its own 6 loads outstanding -> drain to 0
    __builtin_amdgcn_sched_barrier(0);
    asm volatile("s_waitcnt vmcnt(0)" ::: "memory");
    __builtin_amdgcn_s_barrier();
    asm volatile("" ::: "memory");
    __builtin_amdgcn_sched_barrier(0);
    COMPUTE(bc);

    // epilogue — 32x32 C/D layout: col = lane&31, row = (r&3)+8*(r>>2)+4*hi
    float* Cf = (float*)p.C + bz * p.sC;
    unsigned short* Ch = (unsigned short*)p.C + bz * p.sC;
    const float* resid = RESID ? (p.resid + bz * p.sR) : nullptr;
    const int N = p.N;

    #pragma unroll
    for (int mt = 0; mt < 4; ++mt) {
        #pragma unroll
        for (int r = 0; r < 16; ++r) {
            const int row = m0 + mt * 32 + (r & 3) + 8 * (r >> 2) + 4 * hi;
            float rv = 0.0f;
            if constexpr (EXPM == 2) rv = 1.0f / acc1[mt][r];
            const float bm = (BIAS_MODE == 1) ? p.bias[row] : 0.0f;
            #pragma unroll
            for (int nt = 0; nt < 2; ++nt) {
                const int col = n0 + wave * 64 + nt * 32 + ln31;
                float val = acc[mt][nt][r];
                if constexpr (EXPM == 1) {
                    val = __expf(val * p.scale);
                } else {
                    if (BIAS_MODE == 1) val += bm;
                    if (BIAS_MODE == 2) val += p.bias[col];
                    if constexpr (EXPM == 2) val *= rv;
                }
                const long o = (long)row * N + col;
                if (RESID) val += resid[o];
                if (OUT_F32) Cf[o] = val;
                else         Ch[o] = f2bf(val);
            }
        }
    }
}

template<bool OUT_F32, int BIAS_MODE, bool RESID, int EXPM>
__global__ __launch_bounds__(256, 2) void gemm_bt_mfma(GemmP p)
{
    __shared__ unsigned short Als[3 * 4096];   // 24 KB (triple-buffered A)
    __shared__ unsigned short Bls[3 * 8192];   // 48 KB (triple-buffered B)
    gemm_body<OUT_F32, BIAS_MODE, RESID, EXPM>(p, blockIdx.x, Als, Bls);
}

// q/k GEMM (blocks < split, per-n bias) + v GEMM (blocks >= split, per-m bias)
// in a single dispatch: independent producers, both read xT; tail-overlap.
__global__ __launch_bounds__(256, 2) void gemm_qkv_fused(GemmP pqk, GemmP pv, int split)
{
    __shared__ unsigned short Als[3 * 4096];
    __shared__ unsigned short Bls[3 * 8192];
    if ((int)blockIdx.x < split)
        gemm_body<false, 2, false, 0>(pqk, blockIdx.x, Als, Bls);
    else
        gemm_body<false, 1, false, 0>(pv, blockIdx.x - split, Als, Bls);
}

// ---------------------------------------------------------------------------
// prep_all: blocks 0..8191   -> transpose+cast x [B,512,1024] f32 -> xT bf16
//           blocks 8192..9215 -> cast 4 weights to bf16
//           block  9216       -> concat bias [bq;bk]
// ---------------------------------------------------------------------------
__global__ __launch_bounds__(256) void prep_all(
    const float* __restrict__ x, unsigned short* __restrict__ xT,
    const float* __restrict__ Wq, const float* __restrict__ Wk,
    const float* __restrict__ Wv, const float* __restrict__ Wo,
    const float* __restrict__ bq, const float* __restrict__ bk,
    unsigned short* __restrict__ Wb, float* __restrict__ biasqk)
{
    const int b = blockIdx.x;
    const int t = threadIdx.x;
    if (b < 8192) {
        __shared__ float tl[32][33];
        const int batch = b >> 9;
        const int rem = b & 511;
        const int p0 = (rem & 31) * 32;    // HW tile
        const int c0 = (rem >> 5) * 32;    // C tile
        const float* xb = x + (long)batch * 524288;
        unsigned short* xTb = xT + (long)batch * 524288;
        const int tx = t & 31;
        const int ty = t >> 5;             // 0..7
        #pragma unroll
        for (int i = 0; i < 4; ++i)
            tl[ty + 8 * i][tx] = xb[(long)(c0 + ty + 8 * i) * 1024 + p0 + tx];
        __syncthreads();
        #pragma unroll
        for (int i = 0; i < 4; ++i)
            xTb[(long)(p0 + ty + 8 * i) * 512 + c0 + tx] = f2bf(tl[tx][ty + 8 * i]);
    } else if (b < 9216) {
        const int wb = b - 8192;
        const float* srcs[4] = {Wq, Wk, Wv, Wo};
        const float* s = srcs[wb >> 8];
        unsigned short* d = Wb + (long)(wb >> 8) * 262144;
        const int i = ((wb & 255) * 256 + t) * 4;
        const float4 f = *(const float4*)(s + i);
        ushort4 h;
        h.x = f2bf(f.x); h.y = f2bf(f.y); h.z = f2bf(f.z); h.w = f2bf(f.w);
        *(ushort4*)(d + i) = h;
    } else {
        biasqk[t]       = bq[t];
        biasqk[256 + t] = bq[256 + t];
        biasqk[512 + t] = bk[t];
        biasqk[768 + t] = bk[256 + t];
    }
}

// ---------------------------------------------------------------------------
extern "C" void kernel_launch(void* const* d_in, const int* in_sizes, int n_in,
                              void* d_out, int out_size, void* d_ws, size_t ws_size,
                              hipStream_t stream)
{
    const float* x  = (const float*)d_in[0];
    const float* Wq = (const float*)d_in[1];
    const float* bq = (const float*)d_in[2];
    const float* Wk = (const float*)d_in[3];
    const float* bk = (const float*)d_in[4];
    const float* Wv = (const float*)d_in[5];
    const float* bv = (const float*)d_in[6];
    const float* Wo = (const float*)d_in[7];
    const float* bo = (const float*)d_in[8];
    float* out = (float*)d_out;

    const int Bn = 16, C = 512, HW = 1024;
    const long CHW = (long)C * HW;     // 524288
    const long SHW = (long)HW * HW;    // 1048576

    // workspace layout (~103 MB)
    unsigned short* xT   = (unsigned short*)d_ws;        // 16 MB (reused as OT)
    unsigned short* qkT  = xT + Bn * CHW;                // 32 MB  [HW, 2C]
    unsigned short* vB   = qkT + Bn * SHW;               // 16 MB  [C, HW]
    unsigned short* expS = vB + Bn * CHW;                // 32 MB  [HW, HW]
    unsigned short* Wb   = expS + Bn * SHW;              // 2 MB
    float* biasqk = (float*)(Wb + 4 * 262144);           // 4 KB
    unsigned short* OT = xT;

    unsigned short* Wvb = Wb + 2 * 262144;
    unsigned short* Wob = Wb + 3 * 262144;

    const dim3 blk(256);
    const float scale = 0.044194173824159216f;  // 1/sqrt(512)

    prep_all<<<dim3(9217), blk, 0, stream>>>(x, xT, Wq, Wk, Wv, Wo, bq, bk,
                                             Wb, biasqk);

    // qkT = xT·[Wq;Wk]^T + [bq;bk] : M=1024, N=1024, K=512 (8 x 4 tiles)
    GemmP pqk = { xT, Wb, qkT, biasqk, nullptr,
                  HW, 2 * C, C, C, C, CHW, 0, SHW, 0, 2, 5, 0.0f };
    // v = Wv·xT^T + bv : M=512, N=1024, K=512 (4 x 4 tiles)
    GemmP pv  = { Wvb, xT, vB, bv, nullptr,
                  C, HW, C, C, C, 0, CHW, CHW, 0, 2, 4, 0.0f };
    gemm_qkv_fused<<<dim3(768), blk, 0, stream>>>(pqk, pv, 512);

    // expS = exp(scale·q·k) : M=N=1024, K=512 (8 x 4 tiles)
    GemmP ps  = { qkT, qkT + C, expS, nullptr, nullptr,
                  HW, HW, C, 2 * C, 2 * C, SHW, SHW, SHW, 0, 2, 5, scale };
    gemm_bt_mfma<false, 0, false, 1><<<dim3(512), blk, 0, stream>>>(ps);

    // OT = expS·v^T ÷ rowsum(expS) : M=1024, N=512, K=1024 (8 x 2 tiles)
    GemmP po  = { expS, vB, OT, nullptr, nullptr,
                  HW, C, HW, HW, HW, SHW, CHW, CHW, 0, 1, 4, 0.0f };
    gemm_bt_mfma<false, 0, false, 2><<<dim3(256), blk, 0, stream>>>(po);

    // out = Wo·OT^T + bo + x : M=512, N=1024, K=512 (4 x 4 tiles)
    GemmP pout = { Wob, OT, out, bo, x,
                   C, HW, C, C, C, 0, CHW, CHW, CHW, 2, 4, 0.0f };
    gemm_bt_mfma<true, 1, true, 0><<<dim3(256), blk, 0, stream>>>(pout);
}

// Round 6
// 219.682 us; speedup vs baseline: 1.1372x; 1.1372x over previous
//
#include <hip/hip_runtime.h>
#include <hip/hip_bf16.h>
#include <math.h>

// SpatialSelfAttention — B=16, C=512, HW=1024, fp32 in/out, bf16 MFMA internals.
//
// Softmax trick: scaled scores ~ N(0,1), exp() without max-subtraction safe ->
// softmax fuses into GEMM epilogues:
//   expS = exp(scale * qT·kT^T)   (S GEMM epilogue)
//   OT   = (expS · v^T) / l       (O GEMM; l computed in-kernel via ones-MFMA)
//
// Round-10: REVERT to the round-0 16x16-fragment base (best measured:
// every GEMM <40us, total 219.6) and apply the one verified-positive lever:
//   * Counted-vmcnt triple-buffer pipeline (round-3->4 isolated +31% on the
//     32x32 base): BK=32 panels, 4 gload_lds/wave/step, s_waitcnt vmcnt(4)
//     per iteration (never 0 in-loop), raw s_barrier, depth-2 prefetch.
//     Ledger: entry outstanding {t:4 oldest, t+1:4}; vmcnt(4) retires
//     exactly buf[t]; STAGE(t+2) overwrites the buffer whose readers all
//     passed the previous barrier (ds_reads complete before MFMA issue,
//     which precedes the sched_barrier(0)+s_barrier); tail peeled vmcnt(0).
//   * m97-linear LDS layout + 16x16 fragments (conflict profile of the
//     round-0 base; all 32x32+swizzle variants measured slower).
//   * ones-MFMA row-sum in O GEMM (validated round 5): S epilogue loses
//     64 shfl_xor + atomics per thread; lsum buffer deleted entirely.
//   * LDS 48 KB -> 3 blocks/CU; round-0 grids (1024-1536 blocks).

typedef __bf16 bf16x8 __attribute__((ext_vector_type(8)));
typedef float  f32x4  __attribute__((ext_vector_type(4)));

__device__ __forceinline__ unsigned short f2bf(float f) {
    unsigned u = __float_as_uint(f);
    u += 0x7fff + ((u >> 16) & 1);          // round-to-nearest-even
    return (unsigned short)(u >> 16);
}

__device__ __forceinline__ void gload_lds16(const void* g, void* l) {
    __builtin_amdgcn_global_load_lds(
        (const __attribute__((address_space(1))) void*)g,
        (__attribute__((address_space(3))) void*)l, 16, 0, 0);
}

struct GemmP {
    const unsigned short* A;
    const unsigned short* B;
    void* C;
    const float* bias;
    const float* resid;
    int M, N, K, ldA, ldB;
    long sA, sB, sC, sR;
    int ln_nn, ln_pb;
    float scale;
};

// ---------------------------------------------------------------------------
// MFMA GEMM body: C[m,n] = sum_k A[m,k]*B[n,k], 16 batches, 1-D grid.
// Block tile 128x128, 4 waves in 2x2 (wave tile 64x64), 16x16x32 MFMA.
// Decode: xcd = L&7 owns batches {2*xcd, 2*xcd+1}; within-batch tiles row-major.
// BIAS_MODE: 0 none, 1 per-m, 2 per-n.
// EXPM: 0 none; 1 = out bf16 exp(val*scale); 2 = out scaled by 1/rowsum,
//       rowsum accumulated in-kernel via ones-MFMA.
// ---------------------------------------------------------------------------
template<bool OUT_F32, int BIAS_MODE, bool RESID, int EXPM>
__device__ __forceinline__ void gemm_body(const GemmP p, int L,
                                          unsigned short* Als,
                                          unsigned short* Bls)
{
    // ---- XCD-aware decode ----
    const int xcd = L & 7;
    const int idx = L >> 3;
    const int bz  = xcd * 2 + (idx >> p.ln_pb);
    const int w   = idx & ((1 << p.ln_pb) - 1);
    const int m0  = (w >> p.ln_nn) << 7;
    const int n0  = (w & ((1 << p.ln_nn) - 1)) << 7;

    const unsigned short* A = p.A + bz * p.sA;
    const unsigned short* B = p.B + bz * p.sB;

    const int tid  = threadIdx.x;
    const int lane = tid & 63;
    const int wave = tid >> 6;       // 0..3
    const int wm   = wave >> 1;      // wave row (0..1)
    const int wn   = wave & 1;       // wave col (0..1)

    // staging coords (m97 linear): chunk = 16 rows x 32 k = 1024 B
    const int ar = lane >> 2;        // 0..15
    const int ak = (lane & 3) * 8;   // 0,8,16,24

    const unsigned short* agp = A + (long)(m0 + wave * 16 + ar) * p.ldA + ak;
    const unsigned short* bgp = B + (long)(n0 + wave * 16 + ar) * p.ldB + ak;
    const long aj = 64L * p.ldA;     // +64 rows
    const long bj = 64L * p.ldB;

    // 16x16x32 fragment coords
    const int fr = lane & 15;        // row within 16-tile
    const int fq = lane >> 4;        // k-quad 0..3

    f32x4 acc[4][4] = {};
    f32x4 acc1[4] = {};              // row-sums (EXPM==2 only)
    bf16x8 ones;
    if constexpr (EXPM == 2) {
        #pragma unroll
        for (int i = 0; i < 8; ++i) ones[i] = (__bf16)1.0f;
    }

    const int nsteps = p.K >> 5;     // BK=32; 16 or 32 steps

    // stage one [128][32] A panel + B panel into buffer sel (4 loads/wave)
    auto STAGE = [&](int sel) {
        unsigned short* a0 = Als + sel * 4096;
        unsigned short* b0 = Bls + sel * 4096;
        gload_lds16(agp,      a0 + wave * 512);
        gload_lds16(agp + aj, a0 + (wave + 4) * 512);
        gload_lds16(bgp,      b0 + wave * 512);
        gload_lds16(bgp + bj, b0 + (wave + 4) * 512);
        agp += 32; bgp += 32;
    };

    // ds_read fragments from buffer sel, run the 16 (+4 ones) MFMAs
    auto COMPUTE = [&](int sel) {
        const unsigned short* Ap = Als + sel * 4096;
        const unsigned short* Bp = Bls + sel * 4096;
        bf16x8 af[4], bfr[4];
        #pragma unroll
        for (int mt = 0; mt < 4; ++mt)
            af[mt] = *(const bf16x8*)&Ap[(wm * 64 + mt * 16 + fr) * 32 + fq * 8];
        #pragma unroll
        for (int nt = 0; nt < 4; ++nt)
            bfr[nt] = *(const bf16x8*)&Bp[(wn * 64 + nt * 16 + fr) * 32 + fq * 8];
        if constexpr (EXPM == 2) {
            #pragma unroll
            for (int mt = 0; mt < 4; ++mt)
                acc1[mt] = __builtin_amdgcn_mfma_f32_16x16x32_bf16(
                    af[mt], ones, acc1[mt], 0, 0, 0);
        }
        #pragma unroll
        for (int mt = 0; mt < 4; ++mt)
            #pragma unroll
            for (int nt = 0; nt < 4; ++nt)
                acc[mt][nt] = __builtin_amdgcn_mfma_f32_16x16x32_bf16(
                    af[mt], bfr[nt], acc[mt][nt], 0, 0, 0);
    };

    // prologue: prefetch steps 0 and 1 (8 loads outstanding per wave)
    STAGE(0);
    STAGE(1);

    // counted-vmcnt main loop: vmcnt(4) retires the oldest panel only.
    int bc = 0, bn = 1, bs = 2;
    for (int t = 0; t < nsteps - 1; ++t) {
        __builtin_amdgcn_sched_barrier(0);
        asm volatile("s_waitcnt vmcnt(4)" ::: "memory");
        __builtin_amdgcn_s_barrier();
        asm volatile("" ::: "memory");
        __builtin_amdgcn_sched_barrier(0);
        if (t + 2 < nsteps) STAGE(bs);
        COMPUTE(bc);
        const int tmp = bc; bc = bn; bn = bs; bs = tmp;
    }
    // peeled last step: only its own 4 loads outstanding -> drain to 0
    __builtin_amdgcn_sched_barrier(0);
    asm volatile("s_waitcnt vmcnt(0)" ::: "memory");
    __builtin_amdgcn_s_barrier();
    asm volatile("" ::: "memory");
    __builtin_amdgcn_sched_barrier(0);
    COMPUTE(bc);

    // epilogue — 16x16 C/D layout: col = lane&15 (fr), row = fq*4 + r
    float* Cf = (float*)p.C + bz * p.sC;
    unsigned short* Ch = (unsigned short*)p.C + bz * p.sC;
    const float* resid = RESID ? (p.resid + bz * p.sR) : nullptr;
    const int N = p.N;

    if constexpr (EXPM == 1) {
        #pragma unroll
        for (int mt = 0; mt < 4; ++mt)
            #pragma unroll
            for (int r = 0; r < 4; ++r) {
                const int row = m0 + wm * 64 + mt * 16 + fq * 4 + r;
                #pragma unroll
                for (int nt = 0; nt < 4; ++nt) {
                    const int col = n0 + wn * 64 + nt * 16 + fr;
                    Ch[(long)row * N + col] = f2bf(__expf(acc[mt][nt][r] * p.scale));
                }
            }
    } else {
        #pragma unroll
        for (int mt = 0; mt < 4; ++mt) {
            float linv[4];
            if constexpr (EXPM == 2) {
                #pragma unroll
                for (int r = 0; r < 4; ++r)
                    linv[r] = 1.0f / acc1[mt][r];
            }
            #pragma unroll
            for (int nt = 0; nt < 4; ++nt) {
                const int col = n0 + wn * 64 + nt * 16 + fr;
                const float bn2 = (BIAS_MODE == 2) ? p.bias[col] : 0.0f;
                #pragma unroll
                for (int r = 0; r < 4; ++r) {
                    const int row = m0 + wm * 64 + mt * 16 + fq * 4 + r;
                    float val = acc[mt][nt][r] + bn2;
                    if (BIAS_MODE == 1) val += p.bias[row];
                    if constexpr (EXPM == 2) val *= linv[r];
                    const long o = (long)row * N + col;
                    if (RESID) val += resid[o];
                    if (OUT_F32) Cf[o] = val;
                    else         Ch[o] = f2bf(val);
                }
            }
        }
    }
}

template<bool OUT_F32, int BIAS_MODE, bool RESID, int EXPM>
__global__ __launch_bounds__(256, 3) void gemm_bt_mfma(GemmP p)
{
    __shared__ unsigned short Als[3 * 4096];   // 24 KB (triple-buffered)
    __shared__ unsigned short Bls[3 * 4096];   // 24 KB
    gemm_body<OUT_F32, BIAS_MODE, RESID, EXPM>(p, blockIdx.x, Als, Bls);
}

// q/k GEMM (blocks < split, per-n bias) + v GEMM (blocks >= split, per-m bias)
// in a single dispatch: independent producers, both read xT; tail-overlap.
__global__ __launch_bounds__(256, 3) void gemm_qkv_fused(GemmP pqk, GemmP pv, int split)
{
    __shared__ unsigned short Als[3 * 4096];
    __shared__ unsigned short Bls[3 * 4096];
    if ((int)blockIdx.x < split)
        gemm_body<false, 2, false, 0>(pqk, blockIdx.x, Als, Bls);
    else
        gemm_body<false, 1, false, 0>(pv, blockIdx.x - split, Als, Bls);
}

// ---------------------------------------------------------------------------
// prep_all: blocks 0..8191   -> transpose+cast x [B,512,1024] f32 -> xT bf16
//           blocks 8192..9215 -> cast 4 weights to bf16
//           block  9216       -> concat bias [bq;bk]
// ---------------------------------------------------------------------------
__global__ __launch_bounds__(256) void prep_all(
    const float* __restrict__ x, unsigned short* __restrict__ xT,
    const float* __restrict__ Wq, const float* __restrict__ Wk,
    const float* __restrict__ Wv, const float* __restrict__ Wo,
    const float* __restrict__ bq, const float* __restrict__ bk,
    unsigned short* __restrict__ Wb, float* __restrict__ biasqk)
{
    const int b = blockIdx.x;
    const int t = threadIdx.x;
    if (b < 8192) {
        __shared__ float tl[32][33];
        const int batch = b >> 9;
        const int rem = b & 511;
        const int p0 = (rem & 31) * 32;    // HW tile
        const int c0 = (rem >> 5) * 32;    // C tile
        const float* xb = x + (long)batch * 524288;
        unsigned short* xTb = xT + (long)batch * 524288;
        const int tx = t & 31;
        const int ty = t >> 5;             // 0..7
        #pragma unroll
        for (int i = 0; i < 4; ++i)
            tl[ty + 8 * i][tx] = xb[(long)(c0 + ty + 8 * i) * 1024 + p0 + tx];
        __syncthreads();
        #pragma unroll
        for (int i = 0; i < 4; ++i)
            xTb[(long)(p0 + ty + 8 * i) * 512 + c0 + tx] = f2bf(tl[tx][ty + 8 * i]);
    } else if (b < 9216) {
        const int wb = b - 8192;
        const float* srcs[4] = {Wq, Wk, Wv, Wo};
        const float* s = srcs[wb >> 8];
        unsigned short* d = Wb + (long)(wb >> 8) * 262144;
        const int i = ((wb & 255) * 256 + t) * 4;
        const float4 f = *(const float4*)(s + i);
        ushort4 h;
        h.x = f2bf(f.x); h.y = f2bf(f.y); h.z = f2bf(f.z); h.w = f2bf(f.w);
        *(ushort4*)(d + i) = h;
    } else {
        biasqk[t]       = bq[t];
        biasqk[256 + t] = bq[256 + t];
        biasqk[512 + t] = bk[t];
        biasqk[768 + t] = bk[256 + t];
    }
}

// ---------------------------------------------------------------------------
extern "C" void kernel_launch(void* const* d_in, const int* in_sizes, int n_in,
                              void* d_out, int out_size, void* d_ws, size_t ws_size,
                              hipStream_t stream)
{
    const float* x  = (const float*)d_in[0];
    const float* Wq = (const float*)d_in[1];
    const float* bq = (const float*)d_in[2];
    const float* Wk = (const float*)d_in[3];
    const float* bk = (const float*)d_in[4];
    const float* Wv = (const float*)d_in[5];
    const float* bv = (const float*)d_in[6];
    const float* Wo = (const float*)d_in[7];
    const float* bo = (const float*)d_in[8];
    float* out = (float*)d_out;

    const int Bn = 16, C = 512, HW = 1024;
    const long CHW = (long)C * HW;     // 524288
    const long SHW = (long)HW * HW;    // 1048576

    // workspace layout (~103 MB)
    unsigned short* xT   = (unsigned short*)d_ws;        // 16 MB (reused as OT)
    unsigned short* qkT  = xT + Bn * CHW;                // 32 MB  [HW, 2C]
    unsigned short* vB   = qkT + Bn * SHW;               // 16 MB  [C, HW]
    unsigned short* expS = vB + Bn * CHW;                // 32 MB  [HW, HW]
    unsigned short* Wb   = expS + Bn * SHW;              // 2 MB
    float* biasqk = (float*)(Wb + 4 * 262144);           // 4 KB
    unsigned short* OT = xT;

    unsigned short* Wvb = Wb + 2 * 262144;
    unsigned short* Wob = Wb + 3 * 262144;

    const dim3 blk(256);
    const float scale = 0.044194173824159216f;  // 1/sqrt(512)

    prep_all<<<dim3(9217), blk, 0, stream>>>(x, xT, Wq, Wk, Wv, Wo, bq, bk,
                                             Wb, biasqk);

    // qkT = xT·[Wq;Wk]^T + [bq;bk] : M=1024, N=1024, K=512 (8x8 tiles)
    GemmP pqk = { xT, Wb, qkT, biasqk, nullptr,
                  HW, 2 * C, C, C, C, CHW, 0, SHW, 0, 3, 6, 0.0f };
    // v = Wv·xT^T + bv : M=512, N=1024, K=512 (4x8 tiles)
    GemmP pv  = { Wvb, xT, vB, bv, nullptr,
                  C, HW, C, C, C, 0, CHW, CHW, 0, 3, 5, 0.0f };
    gemm_qkv_fused<<<dim3(1536), blk, 0, stream>>>(pqk, pv, 1024);

    // expS = exp(scale·q·k) : M=N=1024, K=512 (8x8 tiles)
    GemmP ps  = { qkT, qkT + C, expS, nullptr, nullptr,
                  HW, HW, C, 2 * C, 2 * C, SHW, SHW, SHW, 0, 3, 6, scale };
    gemm_bt_mfma<false, 0, false, 1><<<dim3(1024), blk, 0, stream>>>(ps);

    // OT = expS·v^T ÷ rowsum(expS) : M=1024, N=512, K=1024 (8x4 tiles)
    GemmP po  = { expS, vB, OT, nullptr, nullptr,
                  HW, C, HW, HW, HW, SHW, CHW, CHW, 0, 2, 5, 0.0f };
    gemm_bt_mfma<false, 0, false, 2><<<dim3(512), blk, 0, stream>>>(po);

    // out = Wo·OT^T + bo + x : M=512, N=1024, K=512 (4x8 tiles)
    GemmP pout = { Wob, OT, out, bo, x,
                   C, HW, C, C, C, 0, CHW, CHW, CHW, 3, 5, 0.0f };
    gemm_bt_mfma<true, 1, true, 0><<<dim3(512), blk, 0, stream>>>(pout);
}

// Round 7
// 216.615 us; speedup vs baseline: 1.1533x; 1.0142x over previous
//
#include <hip/hip_runtime.h>
#include <hip/hip_bf16.h>
#include <math.h>

// SpatialSelfAttention — B=16, C=512, HW=1024, fp32 in/out, bf16 MFMA internals.
//
// Softmax trick: scaled scores ~ N(0,1), exp() without max-subtraction safe ->
// softmax fuses into GEMM epilogues:
//   expS = exp(scale * qT·kT^T)   (S GEMM epilogue)
//   OT   = (expS · v^T) / l       (O GEMM; l computed in-kernel via ones-MFMA)
//
// Round-11 changes (two independent, layout-only edits on the round-10 base):
//   * 2-bit LDS slot swizzle on the 16x16 base. Linear layout measured 3.1M
//     conflict cycles/dispatch: fragment reads have lanes 0-15 at
//     row*64B + fq*16B -> bank quad (row*16)%32 in {0,16} -> 8-way conflict
//     per 16-lane group. phys_slot = fq ^ ((row>>1)&3): rows 0-15 cover all
//     8 bank quads, 2 lanes/bank (free, m136). Write side pre-swizzles the
//     GLOBAL source k-offset (gload_lds LDS dest is DMA-linear, rule #21);
//     read side XORs the same involution. f(row) uses row bits 1-2 only,
//     invariant under the +16/+64 row offsets used by both sides.
//   * prep_all transpose rewritten: 64x64 tiles (2048 blocks), float4 loads,
//     bf16 LDS tile [64][64] with XOR col-swizzle ((c>>3)&7)<<3 (banks
//     hand-checked free both phases), ushort4 stores. Old version was
//     scalar-f32 (16 B/thread) — G13 violation, ~38 us for 52 MB of traffic.
//   * Everything else identical to round-10 (counted-vmcnt triple buffer,
//     ones-MFMA rowsum, qkv fusion, XCD decode, grids).

typedef __bf16 bf16x8 __attribute__((ext_vector_type(8)));
typedef float  f32x4  __attribute__((ext_vector_type(4)));

__device__ __forceinline__ unsigned short f2bf(float f) {
    unsigned u = __float_as_uint(f);
    u += 0x7fff + ((u >> 16) & 1);          // round-to-nearest-even
    return (unsigned short)(u >> 16);
}

__device__ __forceinline__ void gload_lds16(const void* g, void* l) {
    __builtin_amdgcn_global_load_lds(
        (const __attribute__((address_space(1))) void*)g,
        (__attribute__((address_space(3))) void*)l, 16, 0, 0);
}

struct GemmP {
    const unsigned short* A;
    const unsigned short* B;
    void* C;
    const float* bias;
    const float* resid;
    int M, N, K, ldA, ldB;
    long sA, sB, sC, sR;
    int ln_nn, ln_pb;
    float scale;
};

// ---------------------------------------------------------------------------
// MFMA GEMM body: C[m,n] = sum_k A[m,k]*B[n,k], 16 batches, 1-D grid.
// Block tile 128x128, 4 waves in 2x2 (wave tile 64x64), 16x16x32 MFMA.
// Decode: xcd = L&7 owns batches {2*xcd, 2*xcd+1}; within-batch tiles row-major.
// BIAS_MODE: 0 none, 1 per-m, 2 per-n.
// EXPM: 0 none; 1 = out bf16 exp(val*scale); 2 = out scaled by 1/rowsum,
//       rowsum accumulated in-kernel via ones-MFMA.
// ---------------------------------------------------------------------------
template<bool OUT_F32, int BIAS_MODE, bool RESID, int EXPM>
__device__ __forceinline__ void gemm_body(const GemmP p, int L,
                                          unsigned short* Als,
                                          unsigned short* Bls)
{
    // ---- XCD-aware decode ----
    const int xcd = L & 7;
    const int idx = L >> 3;
    const int bz  = xcd * 2 + (idx >> p.ln_pb);
    const int w   = idx & ((1 << p.ln_pb) - 1);
    const int m0  = (w >> p.ln_nn) << 7;
    const int n0  = (w & ((1 << p.ln_nn) - 1)) << 7;

    const unsigned short* A = p.A + bz * p.sA;
    const unsigned short* B = p.B + bz * p.sB;

    const int tid  = threadIdx.x;
    const int lane = tid & 63;
    const int wave = tid >> 6;       // 0..3
    const int wm   = wave >> 1;      // wave row (0..1)
    const int wn   = wave & 1;       // wave col (0..1)

    // staging coords: chunk = 16 rows x 32 k = 1024 B; lane -> (row, slot).
    // GLOBAL k pre-swizzled so LDS phys slot s holds logical slot
    // s ^ f(row), f(row) = (row>>1)&3 (gload_lds dest is DMA-linear).
    const int ar = lane >> 2;                              // 0..15
    const int ak = ((lane & 3) ^ ((ar >> 1) & 3)) * 8;     // swizzled k offset

    const unsigned short* agp = A + (long)(m0 + wave * 16 + ar) * p.ldA + ak;
    const unsigned short* bgp = B + (long)(n0 + wave * 16 + ar) * p.ldB + ak;
    const long aj = 64L * p.ldA;     // +64 rows
    const long bj = 64L * p.ldB;

    // 16x16x32 fragment coords
    const int fr = lane & 15;        // row within 16-tile
    const int fq = lane >> 4;        // k-quad 0..3
    const int kphys = (fq ^ ((fr >> 1) & 3)) * 8;   // swizzled read slot

    f32x4 acc[4][4] = {};
    f32x4 acc1[4] = {};              // row-sums (EXPM==2 only)
    bf16x8 ones;
    if constexpr (EXPM == 2) {
        #pragma unroll
        for (int i = 0; i < 8; ++i) ones[i] = (__bf16)1.0f;
    }

    const int nsteps = p.K >> 5;     // BK=32; 16 or 32 steps

    // stage one [128][32] A panel + B panel into buffer sel (4 loads/wave)
    auto STAGE = [&](int sel) {
        unsigned short* a0 = Als + sel * 4096;
        unsigned short* b0 = Bls + sel * 4096;
        gload_lds16(agp,      a0 + wave * 512);
        gload_lds16(agp + aj, a0 + (wave + 4) * 512);
        gload_lds16(bgp,      b0 + wave * 512);
        gload_lds16(bgp + bj, b0 + (wave + 4) * 512);
        agp += 32; bgp += 32;
    };

    // ds_read fragments from buffer sel, run the 16 (+4 ones) MFMAs
    auto COMPUTE = [&](int sel) {
        const unsigned short* Ap = Als + sel * 4096;
        const unsigned short* Bp = Bls + sel * 4096;
        bf16x8 af[4], bfr[4];
        #pragma unroll
        for (int mt = 0; mt < 4; ++mt)
            af[mt] = *(const bf16x8*)&Ap[(wm * 64 + mt * 16 + fr) * 32 + kphys];
        #pragma unroll
        for (int nt = 0; nt < 4; ++nt)
            bfr[nt] = *(const bf16x8*)&Bp[(wn * 64 + nt * 16 + fr) * 32 + kphys];
        if constexpr (EXPM == 2) {
            #pragma unroll
            for (int mt = 0; mt < 4; ++mt)
                acc1[mt] = __builtin_amdgcn_mfma_f32_16x16x32_bf16(
                    af[mt], ones, acc1[mt], 0, 0, 0);
        }
        #pragma unroll
        for (int mt = 0; mt < 4; ++mt)
            #pragma unroll
            for (int nt = 0; nt < 4; ++nt)
                acc[mt][nt] = __builtin_amdgcn_mfma_f32_16x16x32_bf16(
                    af[mt], bfr[nt], acc[mt][nt], 0, 0, 0);
    };

    // prologue: prefetch steps 0 and 1 (8 loads outstanding per wave)
    STAGE(0);
    STAGE(1);

    // counted-vmcnt main loop: vmcnt(4) retires the oldest panel only.
    int bc = 0, bn = 1, bs = 2;
    for (int t = 0; t < nsteps - 1; ++t) {
        __builtin_amdgcn_sched_barrier(0);
        asm volatile("s_waitcnt vmcnt(4)" ::: "memory");
        __builtin_amdgcn_s_barrier();
        asm volatile("" ::: "memory");
        __builtin_amdgcn_sched_barrier(0);
        if (t + 2 < nsteps) STAGE(bs);
        COMPUTE(bc);
        const int tmp = bc; bc = bn; bn = bs; bs = tmp;
    }
    // peeled last step: only its own 4 loads outstanding -> drain to 0
    __builtin_amdgcn_sched_barrier(0);
    asm volatile("s_waitcnt vmcnt(0)" ::: "memory");
    __builtin_amdgcn_s_barrier();
    asm volatile("" ::: "memory");
    __builtin_amdgcn_sched_barrier(0);
    COMPUTE(bc);

    // epilogue — 16x16 C/D layout: col = lane&15 (fr), row = fq*4 + r
    float* Cf = (float*)p.C + bz * p.sC;
    unsigned short* Ch = (unsigned short*)p.C + bz * p.sC;
    const float* resid = RESID ? (p.resid + bz * p.sR) : nullptr;
    const int N = p.N;

    if constexpr (EXPM == 1) {
        #pragma unroll
        for (int mt = 0; mt < 4; ++mt)
            #pragma unroll
            for (int r = 0; r < 4; ++r) {
                const int row = m0 + wm * 64 + mt * 16 + fq * 4 + r;
                #pragma unroll
                for (int nt = 0; nt < 4; ++nt) {
                    const int col = n0 + wn * 64 + nt * 16 + fr;
                    Ch[(long)row * N + col] = f2bf(__expf(acc[mt][nt][r] * p.scale));
                }
            }
    } else {
        #pragma unroll
        for (int mt = 0; mt < 4; ++mt) {
            float linv[4];
            if constexpr (EXPM == 2) {
                #pragma unroll
                for (int r = 0; r < 4; ++r)
                    linv[r] = 1.0f / acc1[mt][r];
            }
            #pragma unroll
            for (int nt = 0; nt < 4; ++nt) {
                const int col = n0 + wn * 64 + nt * 16 + fr;
                const float bn2 = (BIAS_MODE == 2) ? p.bias[col] : 0.0f;
                #pragma unroll
                for (int r = 0; r < 4; ++r) {
                    const int row = m0 + wm * 64 + mt * 16 + fq * 4 + r;
                    float val = acc[mt][nt][r] + bn2;
                    if (BIAS_MODE == 1) val += p.bias[row];
                    if constexpr (EXPM == 2) val *= linv[r];
                    const long o = (long)row * N + col;
                    if (RESID) val += resid[o];
                    if (OUT_F32) Cf[o] = val;
                    else         Ch[o] = f2bf(val);
                }
            }
        }
    }
}

template<bool OUT_F32, int BIAS_MODE, bool RESID, int EXPM>
__global__ __launch_bounds__(256, 3) void gemm_bt_mfma(GemmP p)
{
    __shared__ unsigned short Als[3 * 4096];   // 24 KB (triple-buffered)
    __shared__ unsigned short Bls[3 * 4096];   // 24 KB
    gemm_body<OUT_F32, BIAS_MODE, RESID, EXPM>(p, blockIdx.x, Als, Bls);
}

// q/k GEMM (blocks < split, per-n bias) + v GEMM (blocks >= split, per-m bias)
// in a single dispatch: independent producers, both read xT; tail-overlap.
__global__ __launch_bounds__(256, 3) void gemm_qkv_fused(GemmP pqk, GemmP pv, int split)
{
    __shared__ unsigned short Als[3 * 4096];
    __shared__ unsigned short Bls[3 * 4096];
    if ((int)blockIdx.x < split)
        gemm_body<false, 2, false, 0>(pqk, blockIdx.x, Als, Bls);
    else
        gemm_body<false, 1, false, 0>(pv, blockIdx.x - split, Als, Bls);
}

// ---------------------------------------------------------------------------
// prep_all: blocks 0..2047   -> transpose+cast x [B,512,1024] f32 -> xT bf16
//                               (64x64 tiles, float4 loads, swizzled bf16 LDS)
//           blocks 2048..3071 -> cast 4 weights to bf16
//           block  3072       -> concat bias [bq;bk]
// ---------------------------------------------------------------------------
__global__ __launch_bounds__(256) void prep_all(
    const float* __restrict__ x, unsigned short* __restrict__ xT,
    const float* __restrict__ Wq, const float* __restrict__ Wk,
    const float* __restrict__ Wv, const float* __restrict__ Wo,
    const float* __restrict__ bq, const float* __restrict__ bk,
    unsigned short* __restrict__ Wb, float* __restrict__ biasqk)
{
    const int b = blockIdx.x;
    const int t = threadIdx.x;
    if (b < 2048) {
        // LDS tile [c=0..63][p=0..63] bf16, col-swizzled: phys p-col =
        // p ^ (((c>>3)&7)<<3). Write: whole-row-constant XOR (4-consec cols
        // preserved, banks free). Read: lanes (sx,sy) hit banks 4*sx+(sy>>1),
        // 2 lanes/bank (free).
        __shared__ unsigned short tlb[64 * 64];
        const int batch = b >> 7;
        const int rem = b & 127;
        const int c0 = (rem >> 4) * 64;   // channel tile
        const int p0 = (rem & 15) * 64;   // pixel tile
        const float* xb = x + (long)batch * 524288;
        unsigned short* xTb = xT + (long)batch * 524288;
        const int lx = t & 15;            // float4 within row
        const int ly = t >> 4;            // 0..15
        #pragma unroll
        for (int i = 0; i < 4; ++i) {
            const int c = ly + 16 * i;
            const float4 f = *(const float4*)&xb[(long)(c0 + c) * 1024 + p0 + lx * 4];
            ushort4 h;
            h.x = f2bf(f.x); h.y = f2bf(f.y); h.z = f2bf(f.z); h.w = f2bf(f.w);
            const int colp = (lx * 4) ^ (((c >> 3) & 7) << 3);
            *(ushort4*)&tlb[c * 64 + colp] = h;
        }
        __syncthreads();
        const int sx = t & 7;             // channel-8 group
        const int sy = t >> 3;            // 0..31
        #pragma unroll
        for (int i = 0; i < 2; ++i) {
            const int r = sy + 32 * i;    // pixel within tile
            ushort4 lo, hi;
            lo.x = tlb[(sx * 8 + 0) * 64 + (r ^ (sx << 3))];
            lo.y = tlb[(sx * 8 + 1) * 64 + (r ^ (sx << 3))];
            lo.z = tlb[(sx * 8 + 2) * 64 + (r ^ (sx << 3))];
            lo.w = tlb[(sx * 8 + 3) * 64 + (r ^ (sx << 3))];
            hi.x = tlb[(sx * 8 + 4) * 64 + (r ^ (sx << 3))];
            hi.y = tlb[(sx * 8 + 5) * 64 + (r ^ (sx << 3))];
            hi.z = tlb[(sx * 8 + 6) * 64 + (r ^ (sx << 3))];
            hi.w = tlb[(sx * 8 + 7) * 64 + (r ^ (sx << 3))];
            unsigned short* o = &xTb[(long)(p0 + r) * 512 + c0 + sx * 8];
            *(ushort4*)o = lo;
            *(ushort4*)(o + 4) = hi;
        }
    } else if (b < 3072) {
        const int wb = b - 2048;
        const float* srcs[4] = {Wq, Wk, Wv, Wo};
        const float* s = srcs[wb >> 8];
        unsigned short* d = Wb + (long)(wb >> 8) * 262144;
        const int i = ((wb & 255) * 256 + t) * 4;
        const float4 f = *(const float4*)(s + i);
        ushort4 h;
        h.x = f2bf(f.x); h.y = f2bf(f.y); h.z = f2bf(f.z); h.w = f2bf(f.w);
        *(ushort4*)(d + i) = h;
    } else {
        biasqk[t]       = bq[t];
        biasqk[256 + t] = bq[256 + t];
        biasqk[512 + t] = bk[t];
        biasqk[768 + t] = bk[256 + t];
    }
}

// ---------------------------------------------------------------------------
extern "C" void kernel_launch(void* const* d_in, const int* in_sizes, int n_in,
                              void* d_out, int out_size, void* d_ws, size_t ws_size,
                              hipStream_t stream)
{
    const float* x  = (const float*)d_in[0];
    const float* Wq = (const float*)d_in[1];
    const float* bq = (const float*)d_in[2];
    const float* Wk = (const float*)d_in[3];
    const float* bk = (const float*)d_in[4];
    const float* Wv = (const float*)d_in[5];
    const float* bv = (const float*)d_in[6];
    const float* Wo = (const float*)d_in[7];
    const float* bo = (const float*)d_in[8];
    float* out = (float*)d_out;

    const int Bn = 16, C = 512, HW = 1024;
    const long CHW = (long)C * HW;     // 524288
    const long SHW = (long)HW * HW;    // 1048576

    // workspace layout (~103 MB)
    unsigned short* xT   = (unsigned short*)d_ws;        // 16 MB (reused as OT)
    unsigned short* qkT  = xT + Bn * CHW;                // 32 MB  [HW, 2C]
    unsigned short* vB   = qkT + Bn * SHW;               // 16 MB  [C, HW]
    unsigned short* expS = vB + Bn * CHW;                // 32 MB  [HW, HW]
    unsigned short* Wb   = expS + Bn * SHW;              // 2 MB
    float* biasqk = (float*)(Wb + 4 * 262144);           // 4 KB
    unsigned short* OT = xT;

    unsigned short* Wvb = Wb + 2 * 262144;
    unsigned short* Wob = Wb + 3 * 262144;

    const dim3 blk(256);
    const float scale = 0.044194173824159216f;  // 1/sqrt(512)

    prep_all<<<dim3(3073), blk, 0, stream>>>(x, xT, Wq, Wk, Wv, Wo, bq, bk,
                                             Wb, biasqk);

    // qkT = xT·[Wq;Wk]^T + [bq;bk] : M=1024, N=1024, K=512 (8x8 tiles)
    GemmP pqk = { xT, Wb, qkT, biasqk, nullptr,
                  HW, 2 * C, C, C, C, CHW, 0, SHW, 0, 3, 6, 0.0f };
    // v = Wv·xT^T + bv : M=512, N=1024, K=512 (4x8 tiles)
    GemmP pv  = { Wvb, xT, vB, bv, nullptr,
                  C, HW, C, C, C, 0, CHW, CHW, 0, 3, 5, 0.0f };
    gemm_qkv_fused<<<dim3(1536), blk, 0, stream>>>(pqk, pv, 1024);

    // expS = exp(scale·q·k) : M=N=1024, K=512 (8x8 tiles)
    GemmP ps  = { qkT, qkT + C, expS, nullptr, nullptr,
                  HW, HW, C, 2 * C, 2 * C, SHW, SHW, SHW, 0, 3, 6, scale };
    gemm_bt_mfma<false, 0, false, 1><<<dim3(1024), blk, 0, stream>>>(ps);

    // OT = expS·v^T ÷ rowsum(expS) : M=1024, N=512, K=1024 (8x4 tiles)
    GemmP po  = { expS, vB, OT, nullptr, nullptr,
                  HW, C, HW, HW, HW, SHW, CHW, CHW, 0, 2, 5, 0.0f };
    gemm_bt_mfma<false, 0, false, 2><<<dim3(512), blk, 0, stream>>>(po);

    // out = Wo·OT^T + bo + x : M=512, N=1024, K=512 (4x8 tiles)
    GemmP pout = { Wob, OT, out, bo, x,
                   C, HW, C, C, C, 0, CHW, CHW, CHW, 3, 5, 0.0f };
    gemm_bt_mfma<true, 1, true, 0><<<dim3(512), blk, 0, stream>>>(pout);
}